// Round 10
// baseline (608.771 us; speedup 1.0000x reference)
//
#include <hip/hip_runtime.h>
#include <cstddef>
#include <cstdint>

// Problem constants: EMBED=1024, NUM_HEADS=16, GQA=4, KV_HEADS=4,
// HEAD_DIM=64, KV_EMBED=256, EPS=1e-3, B=2, T=1024.
#define TSEQ 1024

typedef __attribute__((ext_vector_type(8))) short short8;   // 8 bf16 = 4 VGPRs
typedef __attribute__((ext_vector_type(4))) float floatx4;  // MFMA acc

// Workspace layout (floats):
//  XQ : 2048 x 1024  (2M)
//  XK : 2048 x 256   (0.5M)
//  XVt: 2 x 256 x 1024 (0.5M)  -- V-projection TRANSPOSED: [b][h*64+c][j]
//  XO : 2048 x 1024  (2M)
//  P  : 32 x 1024x1024 (33.55M) -- q=1-p / phi in GROUP-DIAGONAL layout
static constexpr size_t OFF_XQ  = 0;
static constexpr size_t OFF_XK  = (size_t)2 * 1024 * 1024;
static constexpr size_t OFF_XVT = OFF_XK + (size_t)512 * 1024;
static constexpr size_t OFF_XO  = OFF_XVT + (size_t)512 * 1024;
static constexpr size_t OFF_P   = OFF_XO + (size_t)2 * 1024 * 1024;

// GROUP-DIAGONAL LAYOUT (R10): logical cell (r, c) lives at storage row
//   diagrow(r, c>>4) = (((r>>2) + (c>>4)) & 255)*4 + (r&3).
// R=4 rows per step: compute lane t owns cols [16t,16t+16), at step s
// handles row-group g = s - t (rows 4g..4g+3). One step = one contiguous
// 16KB slot (slot = s & 255), read as q and overwritten with phi in place.
// Wrap bijection: slot cells of compute-lane T written at step T+?..: the
// phi cells stored for slot sf are exactly owner lanes T in [sf-255, sf];
// q cells outside that range are preserved (store predicate) for their
// future consumption -- identical masking to the single-wave versions.
//
// R15 DIAGNOSIS: R7-R14 all measured per-step cost ~= (#VMEM instrs) x
// 60-90cy regardless of load path/store pattern/aliasing/reg budget ->
// a single wave can only keep ~8-10 VMEM ops in flight (per-wave
// outstanding limit); at ~600cy latency that is 60-90cy/instr. One wave
// per CU cannot go faster. FIX: producer/consumer block of 5 waves:
// wave 0 computes touching ONLY LDS; waves 1-4 move all global bytes
// (load slot s+2, publish slot s+1 to LDS, flush phi slot s-1). One
// __syncthreads per step; its vmcnt(0) drain overlaps across waves.
// LDS swizzle: cell (k, c=16T+2j+e) <-> dword 1024k+128j+2T+e -> wave-0
// b64 LDS ops are bank-conflict-FREE (bank 2t mod 32); helper accesses
// are 4-way (1.58x, absorbed by helper slack).
// R11 (kept): q-form recurrence, 2 fma/cell, no subs.

// ---------------------------------------------------------------------------
// fp32 -> bf16 hi/lo split (RNE). x ≈ hi + lo with residual ~2^-17 |x|.
// ---------------------------------------------------------------------------
__device__ __forceinline__ void cvt_hi_lo(float x, unsigned short& hi,
                                          unsigned short& lo) {
  unsigned u = __float_as_uint(x);
  unsigned rh = (u + 0x7FFFu + ((u >> 16) & 1u)) & 0xFFFF0000u;
  hi = (unsigned short)(rh >> 16);
  float xl = x - __uint_as_float(rh);
  unsigned ul = __float_as_uint(xl);
  unsigned rl = ul + 0x7FFFu + ((ul >> 16) & 1u);
  lo = (unsigned short)(rl >> 16);
}

__device__ __forceinline__ int diagrow(int r, int cblk) {
  return ((((r >> 2) + cblk) & 255) << 2) | (r & 3);
}

// ---------------------------------------------------------------------------
// Unified NT GEMM core, MFMA bf16x3 (R5-proven).
// ADIAG: A row index mapped through diagrow (reads group-diagonal matrix).
// CDIAG: C row index mapped through diagrow (writes group-diagonal matrix).
// EPI=2 writes q = sigmoid(-x) clipped (R11).
// ---------------------------------------------------------------------------
template <int EPI, int ADIAG, int CDIAG>
__device__ __forceinline__ void mfma_nt_core(
    const float* __restrict__ A, int lda,
    const float* __restrict__ B, int ldb,
    float* __restrict__ C, int ldc, int K,
    const float* __restrict__ bias)
{
  __shared__ __align__(16) unsigned short Ah[64][40];
  __shared__ __align__(16) unsigned short Al[64][40];
  __shared__ __align__(16) unsigned short Bh[64][40];
  __shared__ __align__(16) unsigned short Bl[64][40];

  const int bm = blockIdx.y << 6;
  const int bn = blockIdx.x << 6;
  const int tid  = threadIdx.x;
  const int lane = tid & 63;
  const int wave = tid >> 6;        // 0..3 -> row sub-tile
  const int m16  = lane & 15;
  const int quad = lane >> 4;

  const int srow = tid >> 2;        // staging: row 0..63
  const int skq  = (tid & 3) << 3;  // staging: k offset 0,8,16,24

  floatx4 acc[4];
#pragma unroll
  for (int c = 0; c < 4; ++c) acc[c] = (floatx4){0.f, 0.f, 0.f, 0.f};

  for (int k0 = 0; k0 < K; k0 += 32) {
    {
      const int kq = k0 + skq;
      int arow = bm + srow;
      if (ADIAG) arow = diagrow(arow, kq >> 4);
      const float* ap = A + (size_t)arow * lda + kq;
      const float* bp = B + (size_t)(bn + srow) * ldb + kq;
      float av[8] __attribute__((aligned(16)));
      float bv[8] __attribute__((aligned(16)));
      *(float4*)&av[0] = *(const float4*)(ap);
      *(float4*)&av[4] = *(const float4*)(ap + 4);
      *(float4*)&bv[0] = *(const float4*)(bp);
      *(float4*)&bv[4] = *(const float4*)(bp + 4);
      short8 vah, valo, vbh, vblo;
#pragma unroll
      for (int e = 0; e < 8; ++e) {
        unsigned short h, l;
        cvt_hi_lo(av[e], h, l);
        vah[e] = (short)h; valo[e] = (short)l;
        cvt_hi_lo(bv[e], h, l);
        vbh[e] = (short)h; vblo[e] = (short)l;
      }
      *(short8*)&Ah[srow][skq] = vah;
      *(short8*)&Al[srow][skq] = valo;
      *(short8*)&Bh[srow][skq] = vbh;
      *(short8*)&Bl[srow][skq] = vblo;
    }
    __syncthreads();

    const int arow = (wave << 4) + m16;
    const short8 a_h = *(const short8*)&Ah[arow][quad << 3];
    const short8 a_l = *(const short8*)&Al[arow][quad << 3];
#pragma unroll
    for (int c = 0; c < 4; ++c) {
      const int brow = (c << 4) + m16;
      const short8 b_h = *(const short8*)&Bh[brow][quad << 3];
      const short8 b_l = *(const short8*)&Bl[brow][quad << 3];
      acc[c] = __builtin_amdgcn_mfma_f32_16x16x32_bf16(a_h, b_h, acc[c], 0, 0, 0);
      acc[c] = __builtin_amdgcn_mfma_f32_16x16x32_bf16(a_h, b_l, acc[c], 0, 0, 0);
      acc[c] = __builtin_amdgcn_mfma_f32_16x16x32_bf16(a_l, b_h, acc[c], 0, 0, 0);
    }
    __syncthreads();
  }

#pragma unroll
  for (int c = 0; c < 4; ++c) {
#pragma unroll
    for (int r = 0; r < 4; ++r) {
      const int row = (wave << 4) + (quad << 2) + r;
      const int col = (c << 4) + m16;
      float v = acc[c][r];
      if (EPI == 0) { if (bias) v += bias[bn + col]; }
      if (EPI == 1) { v += bias[bm + row]; }
      if (EPI == 2) {
        // q = 1 - clip(sigmoid(v)) = clip(sigmoid(-v), 0.001, 0.999)
        v = 1.0f / (1.0f + expf(v));
        v = fminf(fmaxf(v, 0.001f), 0.999f);
      }
      int crow = bm + row;
      if (CDIAG) crow = diagrow(crow, (bn + col) >> 4);
      C[(size_t)crow * ldc + (bn + col)] = v;
    }
  }
}

__global__ __launch_bounds__(256) void gemm_nt_mfma_k(
    const float* __restrict__ A, int lda, const float* __restrict__ W, int ldw,
    const float* __restrict__ bias, float* __restrict__ C, int ldc, int K)
{
  mfma_nt_core<0, 0, 0>(A, lda, W, ldw, C, ldc, K, bias);
}

__global__ __launch_bounds__(256) void proj_vt_k(
    const float* __restrict__ vw, const float* __restrict__ value,
    const float* __restrict__ vb, float* __restrict__ XVt)
{
  const int b = blockIdx.z;
  mfma_nt_core<1, 0, 0>(vw, 1024, value + ((size_t)b << 20), 1024,
                        XVt + (size_t)b * 256 * 1024, 1024, 1024, vb);
}

// scores: writes q = 1-p in GROUP-DIAGONAL layout (CDIAG=1)
__global__ __launch_bounds__(256) void scores_mfma_k(
    const float* __restrict__ XQ, const float* __restrict__ XK,
    float* __restrict__ P)
{
  const int z = blockIdx.z;
  const int b = z >> 4;
  mfma_nt_core<2, 0, 1>(XQ + ((size_t)b << 20) + ((size_t)(z & 15) << 6), 1024,
                        XK + (size_t)b * TSEQ * 256 + ((size_t)(z & 3) << 6), 256,
                        P + ((size_t)z << 20), 1024, 64, nullptr);
}

// pv: reads phi (A matrix) from GROUP-DIAGONAL layout (ADIAG=1)
__global__ __launch_bounds__(256) void pv_mfma_k(
    const float* __restrict__ P, const float* __restrict__ XVt,
    float* __restrict__ XO)
{
  const int z = blockIdx.z;
  const int b = z >> 4;
  mfma_nt_core<0, 1, 0>(P + ((size_t)z << 20), 1024,
                        XVt + (size_t)b * 256 * 1024 + (size_t)(z & 3) * 64 * 1024, 1024,
                        XO + ((size_t)b << 20) + ((size_t)(z & 15) << 6), 1024,
                        1024, nullptr);
}

// ---------------------------------------------------------------------------
// Monotonic recurrence, producer/consumer (R15). ONE 5-WAVE BLOCK per z.
// Wave 0: recurrence (q-form), LDS-only. Waves 1-4 (helper h owns in-slot
// row k=h-1): per step s
//   (a) global-load slot (s+2) row k -> regs (consumed NEXT step),
//   (b) ds_write last step's regs (slot s+1) into q-ring Qs[(s+1)&3],
//   (c) ds_read phi slot (s-1) from Pb[(s-1)&1], global-store it
//       (predicated: owner lanes T in [s-1-255, s-1] only -- preserves
//       untouched q cells exactly like the single-wave version).
// One __syncthreads per step orders LDS publication; its vmcnt(0) drain
// is per-wave and overlaps across the 5 waves.
// LDS swizzle: (k, c=16T+2j+e) <-> dword 1024k + 128j + 2T + e.
//   wave-0 b64 ops: bank 2t mod 32 -> conflict-free.
// Cross-lane = __shfl only (DPP failed 3x on gfx950 -- permanently banned).
// ---------------------------------------------------------------------------
__global__ __launch_bounds__(320, 1) void mono_rec_k(float* __restrict__ P)
{
  const int z = blockIdx.x;
  float* __restrict__ Pz = P + ((size_t)z << 20);
  const int tid = threadIdx.x;
  const int w   = tid >> 6;      // 0 = compute wave; 1..4 = helpers
  const int l   = tid & 63;      // lane

  __shared__ __align__(16) float Qs[4 * 4096];   // q ring (64 KB), swizzled
  __shared__ __align__(16) float Pb[2 * 4096];   // phi ring (32 KB), swizzled

  // ---- wave-0 persistent state (helpers simply don't use these) ----
  float b[16];
#pragma unroll
  for (int c = 0; c < 16; ++c) b[c] = 0.0f;
  float phi15h[4], q15h[4];
#pragma unroll
  for (int k = 0; k < 4; ++k) { phi15h[k] = 0.0f; q15h[k] = 0.0f; }

  // ---- helper persistent double buffer (slot data in flight) ----
  float4 bufA[4], bufB[4];

  // ---- prologue: helpers stage slot 0 into ring 0, preload slot 1 ----
  if (w > 0) {
    const int k = w - 1;
    float4 t0[4];
    const float* g0 = Pz + (k << 10) + (l << 2);
#pragma unroll
    for (int m = 0; m < 4; ++m) t0[m] = *(const float4*)(g0 + (m << 8));
    const int base = (k << 10) + ((l & 3) << 8) + ((l >> 2) << 1); // ring 0
#pragma unroll
    for (int m = 0; m < 4; ++m) {
      *(float2*)&Qs[base + (m << 5)]       = make_float2(t0[m].x, t0[m].y);
      *(float2*)&Qs[base + (m << 5) + 128] = make_float2(t0[m].z, t0[m].w);
    }
    const float* g1 = Pz + (1 << 12) + (k << 10) + (l << 2);
#pragma unroll
    for (int m = 0; m < 4; ++m) bufB[m] = *(const float4*)(g1 + (m << 8));
  }
  __syncthreads();

  // ---- compute-wave step ----
  auto cstep = [&](int s) {
    const int rb = (s & 3) << 12;
    float q[4][16];
#pragma unroll
    for (int k = 0; k < 4; ++k)
#pragma unroll
      for (int j = 0; j < 8; ++j) {
        float2 v = *(const float2*)&Qs[rb + (k << 10) + (j << 7) + (l << 1)];
        q[k][2 * j]     = v.x;
        q[k][2 * j + 1] = v.y;
      }
    // boundary batch from lane l-1 (unconditional: sources active)
    float phiL[4], qL[4];
#pragma unroll
    for (int k = 0; k < 4; ++k) {
      phiL[k] = __shfl_up(phi15h[k], 1);
      qL[k]   = __shfl_up(q15h[k], 1);
    }
    const int g = s - l;
    if (g >= 0 && g < 256) {
      const int pbb = (s & 1) << 12;
#pragma unroll
      for (int k = 0; k < 4; ++k) {
        float phi[16];
        if (g == 0 && k == 0) {
#pragma unroll
          for (int c = 0; c < 16; ++c) phi[c] = 0.0f;
          if (l == 0) phi[0] = 1.0f;
        } else {
          const float H0 = (l == 0) ? 0.0f : qL[k];
          float x = fmaf(H0, phiL[k], b[0]);
          phi[0] = x;
#pragma unroll
          for (int c = 1; c < 16; ++c) {
            x = fmaf(q[k][c - 1], x, b[c]);
            phi[c] = x;
          }
        }
#pragma unroll
        for (int c = 0; c < 16; ++c) b[c] = fmaf(-q[k][c], phi[c], phi[c]);
        q15h[k]   = q[k][15];
        phi15h[k] = phi[15];
#pragma unroll
        for (int j = 0; j < 8; ++j)
          *(float2*)&Pb[pbb + (k << 10) + (j << 7) + (l << 1)] =
              make_float2(phi[2 * j], phi[2 * j + 1]);
      }
    }
  };

  // ---- helper step: ld <- slot s+2; publish wr (slot s+1); flush s-1 ----
  auto hstep = [&](int s, float4 (&ld)[4], const float4 (&wr)[4]) {
    const int k = w - 1;
    // (a) issue loads for slot s+2 (ds_written NEXT step)
    const float* gp = Pz + ((size_t)((s + 2) & 255) << 12) + (k << 10) + (l << 2);
#pragma unroll
    for (int m = 0; m < 4; ++m) ld[m] = *(const float4*)(gp + (m << 8));
    // (b) publish slot s+1 into ring (s+1)&3 (swizzled)
    {
      const int base = (((s + 1) & 3) << 12) + (k << 10) +
                       ((l & 3) << 8) + ((l >> 2) << 1);
#pragma unroll
      for (int m = 0; m < 4; ++m) {
        *(float2*)&Qs[base + (m << 5)]       = make_float2(wr[m].x, wr[m].y);
        *(float2*)&Qs[base + (m << 5) + 128] = make_float2(wr[m].z, wr[m].w);
      }
    }
    // (c) flush phi slot s-1 (predicated to valid owner lanes)
    if (s > 0) {
      const int sf = s - 1;
      const int rbase = ((sf & 1) << 12) + (k << 10) +
                        ((l & 3) << 8) + ((l >> 2) << 1);
      float* sp = Pz + ((size_t)(sf & 255) << 12) + (k << 10) + (l << 2);
#pragma unroll
      for (int m = 0; m < 4; ++m) {
        float2 a = *(const float2*)&Pb[rbase + (m << 5)];
        float2 c = *(const float2*)&Pb[rbase + (m << 5) + 128];
        const int T = (m << 4) + (l >> 2);   // owning compute lane
        if (T <= sf && T >= sf - 255)
          *(float4*)(sp + (m << 8)) = make_float4(a.x, a.y, c.x, c.y);
      }
    }
  };

  // ---- main loop: 320 steps, unrolled x2 for helper buffer parity ----
  for (int s0 = 0; s0 < 320; s0 += 2) {
    if (w == 0) cstep(s0); else hstep(s0, bufA, bufB);
    __syncthreads();
    if (w == 0) cstep(s0 + 1); else hstep(s0 + 1, bufB, bufA);
    __syncthreads();
  }
}

// ---------------------------------------------------------------------------
extern "C" void kernel_launch(void* const* d_in, const int* in_sizes, int n_in,
                              void* d_out, int out_size, void* d_ws, size_t ws_size,
                              hipStream_t stream)
{
  const float* query = (const float*)d_in[0];
  const float* key   = (const float*)d_in[1];
  const float* value = (const float*)d_in[2];
  const float* ipw   = (const float*)d_in[3];   // (1536,1024)
  const float* ipb   = (const float*)d_in[4];   // (1536,)
  const float* opw   = (const float*)d_in[5];   // (1024,1024)
  const float* opb   = (const float*)d_in[6];   // (1024,)
  float* out = (float*)d_out;
  float* ws  = (float*)d_ws;

  float* XQ  = ws + OFF_XQ;
  float* XK  = ws + OFF_XK;
  float* XVt = ws + OFF_XVT;
  float* XO  = ws + OFF_XO;
  float* P   = ws + OFF_P;

  // in-projections (MFMA bf16x3)
  gemm_nt_mfma_k<<<dim3(16, 32), 256, 0, stream>>>(
      query, 1024, ipw, 1024, ipb, XQ, 1024, 1024);
  gemm_nt_mfma_k<<<dim3(4, 32), 256, 0, stream>>>(
      key, 1024, ipw + (size_t)1024 * 1024, 1024, ipb + 1024, XK, 256, 1024);
  proj_vt_k<<<dim3(16, 4, 2), 256, 0, stream>>>(
      ipw + (size_t)1280 * 1024, value, ipb + 1280, XVt);

  // scores + sigmoid + clip -> q = 1-p (group-diagonal layout)
  scores_mfma_k<<<dim3(16, 16, 32), 256, 0, stream>>>(XQ, XK, P);

  // monotonic recurrence in place (producer/consumer: 1 compute wave +
  // 4 staging waves per z)
  mono_rec_k<<<dim3(32), dim3(320), 0, stream>>>(P);

  // phi @ V -> XO (NT against transposed V; A read through diagonal map)
  pv_mfma_k<<<dim3(1, 16, 32), 256, 0, stream>>>(P, XVt, XO);

  // out-projection
  gemm_nt_mfma_k<<<dim3(16, 32), 256, 0, stream>>>(
      XO, 1024, opw, 1024, opb, out, 1024, 1024);
}

// Round 12
// 596.527 us; speedup vs baseline: 1.0205x; 1.0205x over previous
//
#include <hip/hip_runtime.h>
#include <cstddef>
#include <cstdint>

// Problem constants: EMBED=1024, NUM_HEADS=16, GQA=4, KV_HEADS=4,
// HEAD_DIM=64, KV_EMBED=256, EPS=1e-3, B=2, T=1024.
#define TSEQ 1024

typedef __attribute__((ext_vector_type(8))) short short8;   // 8 bf16 = 4 VGPRs
typedef __attribute__((ext_vector_type(4))) float floatx4;  // MFMA acc

// Workspace layout (floats):
//  XQ : 2048 x 1024  (2M)
//  XK : 2048 x 256   (0.5M)
//  XVt: 2 x 256 x 1024 (0.5M)  -- V-projection TRANSPOSED: [b][h*64+c][j]
//  XO : 2048 x 1024  (2M)
//  P  : 32 x 1024x1024 (33.55M) -- q=1-p / phi in GROUP-DIAGONAL layout
static constexpr size_t OFF_XQ  = 0;
static constexpr size_t OFF_XK  = (size_t)2 * 1024 * 1024;
static constexpr size_t OFF_XVT = OFF_XK + (size_t)512 * 1024;
static constexpr size_t OFF_XO  = OFF_XVT + (size_t)512 * 1024;
static constexpr size_t OFF_P   = OFF_XO + (size_t)2 * 1024 * 1024;

// GROUP-DIAGONAL LAYOUT (R10): logical cell (r, c) lives at storage row
//   diagrow(r, c>>4) = (((r>>2) + (c>>4)) & 255)*4 + (r&3).
// R=4 rows per step: compute lane t owns cols [16t,16t+16), at step s
// handles row-group g = s - t (rows 4g..4g+3). One step = one contiguous
// 16KB slot (slot = s & 255), read as q and overwritten with phi in place.
// Valid steps: 0..318 (s=319 has no valid lane). Flushed phi cells for
// slot sf are exactly owner lanes T in [sf-255, sf]; other cells keep
// their q values (store predicate) for future consumption.
//
// R16 DIAGNOSIS (R15 autopsy): R15's __syncthreads lowers to
// `s_waitcnt vmcnt(0) lgkmcnt(0); s_barrier` -- each of its 2 barriers
// per step DRAINED the helpers' ~700cy in-flight loads ~200cy after
// issue, destroying the producer/consumer overlap (2300cy/step). Also
// its float2 LDS maps were 4-way-conflicted on the COMPUTE wave's path
// (7.2M SQ_LDS_BANK_CONFLICT). Fixes:
//  (1) raw-asm barrier: `s_waitcnt lgkmcnt(0); s_barrier` ONLY -- loads
//      stay in flight across barriers; the compiler's per-register
//      counted vmcnt (m97-style) orders load->ds_write correctly.
//  (2) LDS layout [ring][k][j=col&15][t=col>>4]: wave-0's b32 ops hit
//      bank t&31 -> 2-way = free; helper 4-way is off critical path.
//  (3) wave 0 runs the EXACT R6 chain (q-form, shuffles, predicates);
//      only q source / phi sink are LDS. Helpers: 8 VMEM/step each
//      (4 loads slot s+2, 4 stores flush slot s-1) -- under the ~8
//      per-wave outstanding-VMEM limit that capped R6-R14 at
//      ~88cy/VMEM-instr, and concurrent across 4 helper waves.
// R17: resubmit of R16 (container failed; kernel audited hang-free:
// uniform barrier counts, bounded addressing, disjoint rings).

// ---------------------------------------------------------------------------
// fp32 -> bf16 hi/lo split (RNE). x ≈ hi + lo with residual ~2^-17 |x|.
// ---------------------------------------------------------------------------
__device__ __forceinline__ void cvt_hi_lo(float x, unsigned short& hi,
                                          unsigned short& lo) {
  unsigned u = __float_as_uint(x);
  unsigned rh = (u + 0x7FFFu + ((u >> 16) & 1u)) & 0xFFFF0000u;
  hi = (unsigned short)(rh >> 16);
  float xl = x - __uint_as_float(rh);
  unsigned ul = __float_as_uint(xl);
  unsigned rl = ul + 0x7FFFu + ((ul >> 16) & 1u);
  lo = (unsigned short)(rl >> 16);
}

__device__ __forceinline__ int diagrow(int r, int cblk) {
  return ((((r >> 2) + cblk) & 255) << 2) | (r & 3);
}

// ---------------------------------------------------------------------------
// Unified NT GEMM core, MFMA bf16x3 (R5-proven).
// ADIAG: A row index mapped through diagrow (reads group-diagonal matrix).
// CDIAG: C row index mapped through diagrow (writes group-diagonal matrix).
// EPI=2 writes q = sigmoid(-x) clipped (R11).
// ---------------------------------------------------------------------------
template <int EPI, int ADIAG, int CDIAG>
__device__ __forceinline__ void mfma_nt_core(
    const float* __restrict__ A, int lda,
    const float* __restrict__ B, int ldb,
    float* __restrict__ C, int ldc, int K,
    const float* __restrict__ bias)
{
  __shared__ __align__(16) unsigned short Ah[64][40];
  __shared__ __align__(16) unsigned short Al[64][40];
  __shared__ __align__(16) unsigned short Bh[64][40];
  __shared__ __align__(16) unsigned short Bl[64][40];

  const int bm = blockIdx.y << 6;
  const int bn = blockIdx.x << 6;
  const int tid  = threadIdx.x;
  const int lane = tid & 63;
  const int wave = tid >> 6;        // 0..3 -> row sub-tile
  const int m16  = lane & 15;
  const int quad = lane >> 4;

  const int srow = tid >> 2;        // staging: row 0..63
  const int skq  = (tid & 3) << 3;  // staging: k offset 0,8,16,24

  floatx4 acc[4];
#pragma unroll
  for (int c = 0; c < 4; ++c) acc[c] = (floatx4){0.f, 0.f, 0.f, 0.f};

  for (int k0 = 0; k0 < K; k0 += 32) {
    {
      const int kq = k0 + skq;
      int arow = bm + srow;
      if (ADIAG) arow = diagrow(arow, kq >> 4);
      const float* ap = A + (size_t)arow * lda + kq;
      const float* bp = B + (size_t)(bn + srow) * ldb + kq;
      float av[8] __attribute__((aligned(16)));
      float bv[8] __attribute__((aligned(16)));
      *(float4*)&av[0] = *(const float4*)(ap);
      *(float4*)&av[4] = *(const float4*)(ap + 4);
      *(float4*)&bv[0] = *(const float4*)(bp);
      *(float4*)&bv[4] = *(const float4*)(bp + 4);
      short8 vah, valo, vbh, vblo;
#pragma unroll
      for (int e = 0; e < 8; ++e) {
        unsigned short h, l;
        cvt_hi_lo(av[e], h, l);
        vah[e] = (short)h; valo[e] = (short)l;
        cvt_hi_lo(bv[e], h, l);
        vbh[e] = (short)h; vblo[e] = (short)l;
      }
      *(short8*)&Ah[srow][skq] = vah;
      *(short8*)&Al[srow][skq] = valo;
      *(short8*)&Bh[srow][skq] = vbh;
      *(short8*)&Bl[srow][skq] = vblo;
    }
    __syncthreads();

    const int arow = (wave << 4) + m16;
    const short8 a_h = *(const short8*)&Ah[arow][quad << 3];
    const short8 a_l = *(const short8*)&Al[arow][quad << 3];
#pragma unroll
    for (int c = 0; c < 4; ++c) {
      const int brow = (c << 4) + m16;
      const short8 b_h = *(const short8*)&Bh[brow][quad << 3];
      const short8 b_l = *(const short8*)&Bl[brow][quad << 3];
      acc[c] = __builtin_amdgcn_mfma_f32_16x16x32_bf16(a_h, b_h, acc[c], 0, 0, 0);
      acc[c] = __builtin_amdgcn_mfma_f32_16x16x32_bf16(a_h, b_l, acc[c], 0, 0, 0);
      acc[c] = __builtin_amdgcn_mfma_f32_16x16x32_bf16(a_l, b_h, acc[c], 0, 0, 0);
    }
    __syncthreads();
  }

#pragma unroll
  for (int c = 0; c < 4; ++c) {
#pragma unroll
    for (int r = 0; r < 4; ++r) {
      const int row = (wave << 4) + (quad << 2) + r;
      const int col = (c << 4) + m16;
      float v = acc[c][r];
      if (EPI == 0) { if (bias) v += bias[bn + col]; }
      if (EPI == 1) { v += bias[bm + row]; }
      if (EPI == 2) {
        // q = 1 - clip(sigmoid(v)) = clip(sigmoid(-v), 0.001, 0.999)
        v = 1.0f / (1.0f + expf(v));
        v = fminf(fmaxf(v, 0.001f), 0.999f);
      }
      int crow = bm + row;
      if (CDIAG) crow = diagrow(crow, (bn + col) >> 4);
      C[(size_t)crow * ldc + (bn + col)] = v;
    }
  }
}

__global__ __launch_bounds__(256) void gemm_nt_mfma_k(
    const float* __restrict__ A, int lda, const float* __restrict__ W, int ldw,
    const float* __restrict__ bias, float* __restrict__ C, int ldc, int K)
{
  mfma_nt_core<0, 0, 0>(A, lda, W, ldw, C, ldc, K, bias);
}

__global__ __launch_bounds__(256) void proj_vt_k(
    const float* __restrict__ vw, const float* __restrict__ value,
    const float* __restrict__ vb, float* __restrict__ XVt)
{
  const int b = blockIdx.z;
  mfma_nt_core<1, 0, 0>(vw, 1024, value + ((size_t)b << 20), 1024,
                        XVt + (size_t)b * 256 * 1024, 1024, 1024, vb);
}

// scores: writes q = 1-p in GROUP-DIAGONAL layout (CDIAG=1)
__global__ __launch_bounds__(256) void scores_mfma_k(
    const float* __restrict__ XQ, const float* __restrict__ XK,
    float* __restrict__ P)
{
  const int z = blockIdx.z;
  const int b = z >> 4;
  mfma_nt_core<2, 0, 1>(XQ + ((size_t)b << 20) + ((size_t)(z & 15) << 6), 1024,
                        XK + (size_t)b * TSEQ * 256 + ((size_t)(z & 3) << 6), 256,
                        P + ((size_t)z << 20), 1024, 64, nullptr);
}

// pv: reads phi (A matrix) from GROUP-DIAGONAL layout (ADIAG=1)
__global__ __launch_bounds__(256) void pv_mfma_k(
    const float* __restrict__ P, const float* __restrict__ XVt,
    float* __restrict__ XO)
{
  const int z = blockIdx.z;
  const int b = z >> 4;
  mfma_nt_core<0, 1, 0>(P + ((size_t)z << 20), 1024,
                        XVt + (size_t)b * 256 * 1024 + (size_t)(z & 3) * 64 * 1024, 1024,
                        XO + ((size_t)b << 20) + ((size_t)(z & 15) << 6), 1024,
                        1024, nullptr);
}

// ---------------------------------------------------------------------------
// Monotonic recurrence, producer/consumer v2 (R16/R17). ONE 5-WAVE BLOCK
// per z. Wave 0 = exact R6 step body (q-form, shuffles, predicates) with
// LDS q-source / LDS phi-sink. Waves 1..4 (helper h owns in-slot row
// k=h-1): load slot s+2 (coalesced float4), publish slot s+1 to
// Qr[(s+1)&1], flush phi slot s-1 from Pr[(s-1)&1] to global (predicated
// to valid owner lanes). Raw barrier = lgkmcnt(0) + s_barrier (NO vmcnt
// drain -- helper loads stay in flight across barriers).
// Cross-lane = __shfl only (DPP failed 3x on gfx950 -- permanently banned).
// ---------------------------------------------------------------------------
#define MONO_BAR() do {                                          \
    asm volatile("s_waitcnt lgkmcnt(0)" ::: "memory");           \
    __builtin_amdgcn_sched_barrier(0);                           \
    asm volatile("s_barrier" ::: "memory");                      \
    __builtin_amdgcn_sched_barrier(0);                           \
  } while (0)

__global__ __launch_bounds__(320, 1) void mono_rec_k(float* __restrict__ P)
{
  const int z = blockIdx.x;
  float* __restrict__ Pz = P + ((size_t)z << 20);
  const int tid = threadIdx.x;
  const int w   = tid >> 6;      // 0 = compute wave; 1..4 = helpers
  const int l   = tid & 63;      // lane

  // LDS: [ring2][k4][j16][t64] -- bank = t&31 for wave-0 b32 ops (free).
  __shared__ float Qr[2][4][16][64];   // q slots      (32 KB)
  __shared__ float Pr[2][4][16][64];   // phi slots    (32 KB)

  // ---- wave-0 persistent state ----
  float b[16];
  float phi15h[4], q15h[4];
#pragma unroll
  for (int c = 0; c < 16; ++c) b[c] = 0.0f;
#pragma unroll
  for (int k = 0; k < 4; ++k) { phi15h[k] = 0.0f; q15h[k] = 0.0f; }

  // ---- helper persistent buffers ----
  const int hk = (w > 0) ? (w - 1) : 0;
  float4 bufX[4], bufY[4];

  auto hload = [&](int slot, float4 (&buf)[4]) {
    const float* gp = Pz + ((size_t)(slot & 255) << 12) + (hk << 10) + (l << 2);
#pragma unroll
    for (int m = 0; m < 4; ++m) buf[m] = *(const float4*)(gp + (m << 8));
  };
  // publish q slot s1 into Qr[s1&1]; lane l block m = cols 256m+4l..+3
  // -> j = 4(l&3)+i, t = 16m + (l>>2).
  auto hpub = [&](int s1, const float4 (&buf)[4]) {
    const int rb = s1 & 1;
    const int j0 = (l & 3) << 2;
#pragma unroll
    for (int m = 0; m < 4; ++m) {
      const int tt = (m << 4) + (l >> 2);
      Qr[rb][hk][j0 + 0][tt] = buf[m].x;
      Qr[rb][hk][j0 + 1][tt] = buf[m].y;
      Qr[rb][hk][j0 + 2][tt] = buf[m].z;
      Qr[rb][hk][j0 + 3][tt] = buf[m].w;
    }
  };
  // flush phi slot sf from Pr[sf&1] to global (predicated to owner lanes
  // T in [sf-255, sf]; other cells keep q -- in-place preserve).
  auto hflush = [&](int sf) {
    const int rb = sf & 1;
    const int j0 = (l & 3) << 2;
    float* sp = Pz + ((size_t)(sf & 255) << 12) + (hk << 10) + (l << 2);
#pragma unroll
    for (int m = 0; m < 4; ++m) {
      const int T = (m << 4) + (l >> 2);   // owning compute lane, 0..63
      if (T <= sf && T >= sf - 255) {
        float4 v = make_float4(Pr[rb][hk][j0 + 0][T],
                               Pr[rb][hk][j0 + 1][T],
                               Pr[rb][hk][j0 + 2][T],
                               Pr[rb][hk][j0 + 3][T]);
        *(float4*)(sp + (m << 8)) = v;
      }
    }
  };

  // ---- wave-0 step: exact R6 body; q from Qr[s&1], phi to Pr[s&1] ----
  auto cstep = [&](int s) {
    const int rb = s & 1;
    float q[4][16];
#pragma unroll
    for (int k = 0; k < 4; ++k)
#pragma unroll
      for (int j = 0; j < 16; ++j) q[k][j] = Qr[rb][k][j][l];

    float phiL[4], qL[4];
#pragma unroll
    for (int k = 0; k < 4; ++k) {
      phiL[k] = __shfl_up(phi15h[k], 1);
      qL[k]   = __shfl_up(q15h[k], 1);
    }

    const int g = s - l;
    if (g >= 0 && g < 256) {
#pragma unroll
      for (int k = 0; k < 4; ++k) {
        float phi[16];
        if (g == 0 && k == 0) {
#pragma unroll
          for (int c = 0; c < 16; ++c) phi[c] = 0.0f;
          if (l == 0) phi[0] = 1.0f;
        } else {
          const float H0 = (l == 0) ? 0.0f : qL[k];
          float x = fmaf(H0, phiL[k], b[0]);
          phi[0] = x;
#pragma unroll
          for (int c = 1; c < 16; ++c) {
            x = fmaf(q[k][c - 1], x, b[c]);
            phi[c] = x;
          }
        }
#pragma unroll
        for (int c = 0; c < 16; ++c) b[c] = fmaf(-q[k][c], phi[c], phi[c]);
        q15h[k]   = q[k][15];
        phi15h[k] = phi[15];
#pragma unroll
        for (int j = 0; j < 16; ++j) Pr[rb][k][j][l] = phi[j];
      }
    }
  };

  // ---- prologue: helpers stage slot 0 into ring 0, preload slot 1 ----
  if (w > 0) {
    hload(0, bufX);
    hload(1, bufY);
    hpub(0, bufX);      // compiler inserts counted vmcnt for bufX here
  }
  MONO_BAR();

  // ---- step 0: no flush ----
  if (w == 0) cstep(0);
  else { hload(2, bufX); hpub(1, bufY); }
  MONO_BAR();

  // ---- step 1: first flush (slot 0) ----
  if (w == 0) cstep(1);
  else { hload(3, bufY); hpub(2, bufX); hflush(0); }
  MONO_BAR();

  // ---- main loop: s = 2..319 (valid work ends at s=318) ----
  for (int s = 2; s < 320; s += 2) {
    if (w == 0) cstep(s);
    else { hload(s + 2, bufX); hpub(s + 1, bufY); hflush(s - 1); }
    MONO_BAR();
    if (w == 0) cstep(s + 1);
    else { hload(s + 3, bufY); hpub(s + 2, bufX); hflush(s); }
    MONO_BAR();
  }
  // flushes covered slots 0..318 = all valid steps (s=319 has no valid lane).
}

// ---------------------------------------------------------------------------
extern "C" void kernel_launch(void* const* d_in, const int* in_sizes, int n_in,
                              void* d_out, int out_size, void* d_ws, size_t ws_size,
                              hipStream_t stream)
{
  const float* query = (const float*)d_in[0];
  const float* key   = (const float*)d_in[1];
  const float* value = (const float*)d_in[2];
  const float* ipw   = (const float*)d_in[3];   // (1536,1024)
  const float* ipb   = (const float*)d_in[4];   // (1536,)
  const float* opw   = (const float*)d_in[5];   // (1024,1024)
  const float* opb   = (const float*)d_in[6];   // (1024,)
  float* out = (float*)d_out;
  float* ws  = (float*)d_ws;

  float* XQ  = ws + OFF_XQ;
  float* XK  = ws + OFF_XK;
  float* XVt = ws + OFF_XVT;
  float* XO  = ws + OFF_XO;
  float* P   = ws + OFF_P;

  // in-projections (MFMA bf16x3)
  gemm_nt_mfma_k<<<dim3(16, 32), 256, 0, stream>>>(
      query, 1024, ipw, 1024, ipb, XQ, 1024, 1024);
  gemm_nt_mfma_k<<<dim3(4, 32), 256, 0, stream>>>(
      key, 1024, ipw + (size_t)1024 * 1024, 1024, ipb + 1024, XK, 256, 1024);
  proj_vt_k<<<dim3(16, 4, 2), 256, 0, stream>>>(
      ipw + (size_t)1280 * 1024, value, ipb + 1280, XVt);

  // scores + sigmoid + clip -> q = 1-p (group-diagonal layout)
  scores_mfma_k<<<dim3(16, 16, 32), 256, 0, stream>>>(XQ, XK, P);

  // monotonic recurrence in place (producer/consumer v2: raw barriers,
  // counted vmcnt, conflict-free compute-wave LDS)
  mono_rec_k<<<dim3(32), dim3(320), 0, stream>>>(P);

  // phi @ V -> XO (NT against transposed V; A read through diagonal map)
  pv_mfma_k<<<dim3(1, 16, 32), 256, 0, stream>>>(P, XVt, XO);

  // out-projection
  gemm_nt_mfma_k<<<dim3(16, 32), 256, 0, stream>>>(
      XO, 1024, opw, 1024, opb, out, 1024, 1024);
}